// Round 1
// 157.789 us; speedup vs baseline: 1.0364x; 1.0364x over previous
//
#include <hip/hip_runtime.h>
#include <cmath>

#define Tn  2048
#define Cn  1024
#define Hn  64
#define BTn 16384

typedef _Float16 f16x8 __attribute__((ext_vector_type(8)));
typedef _Float16 f16x4 __attribute__((ext_vector_type(4)));
typedef _Float16 f16x2 __attribute__((ext_vector_type(2)));
typedef float    f32x4 __attribute__((ext_vector_type(4)));

// ---------------------------------------------------------------------------
// prep: transpose Wq|Wk|Wv (each [Cn][64] fp32) into Wt[192][Cn] f16
// ---------------------------------------------------------------------------
__global__ __launch_bounds__(256) void prep_w_kernel(
    const float* __restrict__ Wq, const float* __restrict__ Wk,
    const float* __restrict__ Wv, _Float16* __restrict__ Wt)
{
    __shared__ float ts[64][65];
    const int blk = blockIdx.x;          // 48 = 3 proj * 16 c-tiles
    const int p   = blk >> 4;
    const int c0  = (blk & 15) * 64;
    const float* __restrict__ W = (p == 0) ? Wq : (p == 1) ? Wk : Wv;
    const int tid = threadIdx.x;
    #pragma unroll
    for (int it = 0; it < 16; it++) {
        int idx = tid + it * 256;
        int c = idx >> 6, n = idx & 63;
        ts[c][n] = W[(size_t)(c0 + c) * Hn + n];
    }
    __syncthreads();
    #pragma unroll
    for (int it = 0; it < 16; it++) {
        int idx = tid + it * 256;
        int n = idx >> 6, c = idx & 63;
        Wt[(size_t)(p * 64 + n) * Cn + c0 + c] = (_Float16)ts[c][n];
    }
}

// ---------------------------------------------------------------------------
// proj: barrier-light K-loop. Block = 32 rows x all 192 out-cols. 4 waves;
// wave w owns n-range [w*48, w*48+48) x 32 rows (2m x 3n MFMA tiles).
// x-tile staged to LDS in TWO K-halves of 512 (f16, row stride 520 f16 =
// 260 dwords = 4 mod 32: conflict-free quarter-wave frag reads) so LDS is
// 33 KB -> 4 blocks/CU = 4 waves/SIMD (was 66 KB / 2 blocks / 2 waves:
// latency-bound, MfmaUtil 4.7%). W B-frags read directly from global
// (Wt is 384 KB, L2-resident) interleaved with MFMA.
// Epilogue: RoPE on q/k (q pre-scaled H^-1/2), v written TRANSPOSED
// vT[b][h][t] so attn can read PV B-frags straight from global.
// ---------------------------------------------------------------------------
#define XS2 520    // 512 + 8 pad; 1040 B row stride = 260 dwords ≡ 4 (mod 32)

__global__ __launch_bounds__(256, 4) void proj_kernel(
    const float* __restrict__ x, const _Float16* __restrict__ Wt,
    _Float16* __restrict__ qh, _Float16* __restrict__ kh, _Float16* __restrict__ vT)
{
    __shared__ _Float16 xs[32 * XS2];    // 33.3 KB -> 4 blocks/CU
    const int row0 = blockIdx.x * 32;
    const int tid  = threadIdx.x;
    const int wave = tid >> 6, lane = tid & 63;
    const int quad = lane >> 4, l15 = lane & 15;

    f32x4 acc[2][3] = {};
    const _Float16* __restrict__ wb = Wt + (size_t)(wave * 48 + l15) * Cn + quad * 8;

    #pragma unroll
    for (int ph = 0; ph < 2; ph++) {
        if (ph) __syncthreads();         // all waves done reading half 0
        // Stage 32 rows x 512 fp32 -> f16. Coalesced float4 reads.
        #pragma unroll 8
        for (int it = 0; it < 16; it++) {
            int idx = tid + it * 256;    // 4096 float4 per half
            int r = idx >> 7, c4 = idx & 127;
            float4 xv = *(const float4*)&x[(size_t)(row0 + r) * Cn + ph * 512 + c4 * 4];
            f16x4 hv = { (_Float16)xv.x, (_Float16)xv.y, (_Float16)xv.z, (_Float16)xv.w };
            *(f16x4*)&xs[r * XS2 + c4 * 4] = hv;
        }
        __syncthreads();

        const _Float16* __restrict__ wp = wb + ph * 512;
        #pragma unroll 4
        for (int kc = 0; kc < 512; kc += 32) {
            f16x8 b0 = *(const f16x8*)&wp[kc];
            f16x8 b1 = *(const f16x8*)&wp[16 * Cn + kc];
            f16x8 b2 = *(const f16x8*)&wp[32 * Cn + kc];
            f16x8 a0 = *(const f16x8*)&xs[(     l15) * XS2 + kc + quad * 8];
            f16x8 a1 = *(const f16x8*)&xs[(16 + l15) * XS2 + kc + quad * 8];
            acc[0][0] = __builtin_amdgcn_mfma_f32_16x16x32_f16(a0, b0, acc[0][0], 0, 0, 0);
            acc[1][0] = __builtin_amdgcn_mfma_f32_16x16x32_f16(a1, b0, acc[1][0], 0, 0, 0);
            acc[0][1] = __builtin_amdgcn_mfma_f32_16x16x32_f16(a0, b1, acc[0][1], 0, 0, 0);
            acc[1][1] = __builtin_amdgcn_mfma_f32_16x16x32_f16(a1, b1, acc[1][1], 0, 0, 0);
            acc[0][2] = __builtin_amdgcn_mfma_f32_16x16x32_f16(a0, b2, acc[0][2], 0, 0, 0);
            acc[1][2] = __builtin_amdgcn_mfma_f32_16x16x32_f16(a1, b2, acc[1][2], 0, 0, 0);
        }
    }

    // Epilogue
    const int bidx = row0 >> 11;
    #pragma unroll
    for (int nt = 0; nt < 3; nt++) {
        const int n = wave * 48 + nt * 16 + l15;
        const int p = n >> 6;            // uniform per (wave,nt)
        const int h = n & 63;
        if (p < 2) {                     // q or k: RoPE
            _Float16* __restrict__ outb = (p == 0) ? qh : kh;
            const float invf = __expf(-0.2878231366242557f * (float)(h >> 1));
            #pragma unroll
            for (int mt = 0; mt < 2; mt++) {
                #pragma unroll
                for (int r = 0; r < 4; r++) {
                    int   row = row0 + mt * 16 + quad * 4 + r;
                    float val = acc[mt][nt][r];
                    float partner = __shfl_xor(val, 1, 64);
                    float ang = (float)(row & (Tn - 1)) * invf;
                    float sv, cv;
                    __sincosf(ang, &sv, &cv);
                    float res = (h & 1) ? fmaf(val, cv,  partner * sv)
                                        : fmaf(val, cv, -partner * sv);
                    if (p == 0) res *= 0.125f;
                    float resn = __shfl_xor(res, 1, 64);
                    if (!(l15 & 1)) {
                        f16x2 pk = { (_Float16)res, (_Float16)resn };
                        *(f16x2*)&outb[(size_t)row * Hn + h] = pk;
                    }
                }
            }
        } else {                         // v: store transposed vT[b][h][t]
            #pragma unroll
            for (int mt = 0; mt < 2; mt++) {
                int t = (row0 & (Tn - 1)) + mt * 16 + quad * 4;
                f16x4 pv = { (_Float16)acc[mt][nt][0], (_Float16)acc[mt][nt][1],
                             (_Float16)acc[mt][nt][2], (_Float16)acc[mt][nt][3] };
                *(f16x4*)&vT[((size_t)bidx * Hn + h) * Tn + t] = pv;
            }
        }
    }
}

// ---------------------------------------------------------------------------
// attn: barrier-free flash loop. QT=16, STL=64, 256 thr = 4 waves; each wave
// processes every 4th s-tile (jt = w, w+4, ...) with its own online-softmax
// state; one barrier + LDS merge at the end. 4 waves (was 2) lifts occupancy
// to 4 waves/SIMD to hide L2 latency + serial softmax chain. K and vT
// B-frags read directly from global (L2: batch working set 768 KB,
// XCD-affine via b = blk&7). qt permuted so each CU's 4 resident blocks
// have constant total work (sum = 254 per CU).
// ---------------------------------------------------------------------------
#define PSP 72

__global__ __launch_bounds__(256, 4) void attn_kernel(
    const _Float16* __restrict__ qh, const _Float16* __restrict__ kh,
    const _Float16* __restrict__ vT, float* __restrict__ out)
{
    __shared__ _Float16 ps[4][16 * PSP];     // wave-private P transpose
    __shared__ float ocomb[4][16][65];
    __shared__ float mlcomb[4][2][16];       // [wave][m|l][row]

    const int blk = blockIdx.x;
    const int b   = blk & 7;                 // batch == XCD affinity
    const int j   = blk >> 3;                // 0..127
    const int jm  = j & 31, g = j >> 5;      // complement permutation:
    const int qt  = (g == 0) ? (127 - jm)    // per-CU resident set sums const
                  : (g == 1) ? (64 + jm)
                  : (g == 2) ? (63 - jm) : jm;
    const int t0  = qt * 16;
    const int tid = threadIdx.x;
    const int w = tid >> 6, lane = tid & 63;
    const int quad = lane >> 4, l15 = lane & 15;

    const _Float16* __restrict__ qb = qh + (size_t)b * Tn * Hn;
    const _Float16* __restrict__ kb = kh + (size_t)b * Tn * Hn;
    const _Float16* __restrict__ vb = vT + (size_t)b * Hn * Tn;

    // Q A-frags: held in registers for the whole loop
    const f16x8 aq0 = *(const f16x8*)&qb[(size_t)(t0 + l15) * Hn +      quad * 8];
    const f16x8 aq1 = *(const f16x8*)&qb[(size_t)(t0 + l15) * Hn + 32 + quad * 8];

    float m_run[4], l_run[4];
    f32x4 oacc[4] = {};
    #pragma unroll
    for (int r = 0; r < 4; r++) { m_run[r] = -1e30f; l_run[r] = 0.0f; }

    const int nst = (t0 + 16 + 63) >> 6;
    for (int jt = w; jt < nst; jt += 4) {
        const int s0 = jt * 64;

        // K B-frags direct from global (16 rows x 64B per load instr)
        f16x8 kf[4][2];
        #pragma unroll
        for (int nt = 0; nt < 4; nt++) {
            const _Float16* kp = &kb[(size_t)(s0 + nt * 16 + l15) * Hn + quad * 8];
            kf[nt][0] = *(const f16x8*)kp;
            kf[nt][1] = *(const f16x8*)(kp + 32);
        }
        f32x4 sacc[4];
        #pragma unroll
        for (int nt = 0; nt < 4; nt++) {
            f32x4 z = {};
            z = __builtin_amdgcn_mfma_f32_16x16x32_f16(aq0, kf[nt][0], z, 0, 0, 0);
            z = __builtin_amdgcn_mfma_f32_16x16x32_f16(aq1, kf[nt][1], z, 0, 0, 0);
            sacc[nt] = z;
        }

        // vT B-frags: issue before softmax (independent), consumed by PV
        f16x8 vf[2][4];
        #pragma unroll
        for (int sc = 0; sc < 2; sc++)
            #pragma unroll
            for (int ht = 0; ht < 4; ht++)
                vf[sc][ht] = *(const f16x8*)&vb[(size_t)(ht * 16 + l15) * Tn
                                                + s0 + sc * 32 + quad * 8];

        if (jt == nst - 1) {             // causal mask: only diagonal tile
            #pragma unroll
            for (int nt = 0; nt < 4; nt++)
                #pragma unroll
                for (int r = 0; r < 4; r++) {
                    int scol = s0 + nt * 16 + l15;
                    int trow = t0 + quad * 4 + r;
                    if (scol > trow) sacc[nt][r] = -1e30f;
                }
        }

        // online softmax (rows = quad*4+r; reduce over the 16 l15 lanes)
        float pr[4][4];
        #pragma unroll
        for (int r = 0; r < 4; r++) {
            float mx = fmaxf(fmaxf(sacc[0][r], sacc[1][r]),
                             fmaxf(sacc[2][r], sacc[3][r]));
            #pragma unroll
            for (int off = 1; off < 16; off <<= 1)
                mx = fmaxf(mx, __shfl_xor(mx, off, 64));
            float mnew  = fmaxf(m_run[r], mx);
            float alpha = __expf(m_run[r] - mnew);
            m_run[r] = mnew;
            float rs = 0.0f;
            #pragma unroll
            for (int nt = 0; nt < 4; nt++) {
                float pv = __expf(sacc[nt][r] - mnew);
                pr[nt][r] = pv; rs += pv;
            }
            #pragma unroll
            for (int off = 1; off < 16; off <<= 1)
                rs += __shfl_xor(rs, off, 64);
            l_run[r] = fmaf(l_run[r], alpha, rs);
            #pragma unroll
            for (int ht = 0; ht < 4; ht++)
                oacc[ht][r] = oacc[ht][r] * alpha;
        }

        // P -> ps (wave-private; same-wave RAW, no barrier)
        #pragma unroll
        for (int nt = 0; nt < 4; nt++)
            #pragma unroll
            for (int r = 0; r < 4; r++) {
                float pv = pr[nt][r];
                float pn = __shfl_xor(pv, 1, 64);
                if (!(l15 & 1)) {
                    f16x2 pk = { (_Float16)pv, (_Float16)pn };
                    *(f16x2*)&ps[w][(quad * 4 + r) * PSP + nt * 16 + l15] = pk;
                }
            }

        // O += P V  (8 MFMA, B-frags already in registers)
        #pragma unroll
        for (int sc = 0; sc < 2; sc++) {
            f16x8 ap = *(const f16x8*)&ps[w][l15 * PSP + sc * 32 + quad * 8];
            #pragma unroll
            for (int ht = 0; ht < 4; ht++)
                oacc[ht] = __builtin_amdgcn_mfma_f32_16x16x32_f16(ap, vf[sc][ht],
                                                                  oacc[ht], 0, 0, 0);
        }
    }

    // Write partials, barrier, merge the four waves' online-softmax states.
    #pragma unroll
    for (int r = 0; r < 4; r++) {
        #pragma unroll
        for (int ht = 0; ht < 4; ht++)
            ocomb[w][quad * 4 + r][ht * 16 + l15] = oacc[ht][r];
        if (l15 == 0) {
            mlcomb[w][0][quad * 4 + r] = m_run[r];
            mlcomb[w][1][quad * 4 + r] = l_run[r];
        }
    }
    __syncthreads();

    // wave w finalizes rows [w*4, w*4+4); 64 lanes = 64 h (coalesced)
    #pragma unroll
    for (int rp = 0; rp < 4; rp++) {
        int row = w * 4 + rp;
        float m0 = mlcomb[0][0][row], m1 = mlcomb[1][0][row];
        float m2 = mlcomb[2][0][row], m3 = mlcomb[3][0][row];
        float mm = fmaxf(fmaxf(m0, m1), fmaxf(m2, m3));
        float a0 = __expf(m0 - mm), a1 = __expf(m1 - mm);
        float a2 = __expf(m2 - mm), a3 = __expf(m3 - mm);
        float ll = mlcomb[0][1][row] * a0 + mlcomb[1][1][row] * a1
                 + mlcomb[2][1][row] * a2 + mlcomb[3][1][row] * a3;
        float ov = (ocomb[0][row][lane] * a0 + ocomb[1][row][lane] * a1
                  + ocomb[2][row][lane] * a2 + ocomb[3][row][lane] * a3) / ll;
        out[((size_t)b * Tn + t0 + row) * Hn + lane] = ov;
    }
}

extern "C" void kernel_launch(void* const* d_in, const int* in_sizes, int n_in,
                              void* d_out, int out_size, void* d_ws, size_t ws_size,
                              hipStream_t stream) {
    const float* x  = (const float*)d_in[0];
    const float* Wq = (const float*)d_in[1];
    const float* Wk = (const float*)d_in[2];
    const float* Wv = (const float*)d_in[3];

    const size_t qkvN = (size_t)BTn * Hn;
    _Float16* qh = (_Float16*)d_ws;
    _Float16* kh = qh + qkvN;
    _Float16* vT = kh + qkvN;                     // [8][64][2048] transposed
    _Float16* Wt = vT + qkvN;                     // [192][1024] f16

    prep_w_kernel<<<48, 256, 0, stream>>>(Wq, Wk, Wv, Wt);
    proj_kernel<<<BTn / 32, 256, 0, stream>>>(x, Wt, qh, kh, vT);
    attn_kernel<<<1024, 256, 0, stream>>>(qh, kh, vT, (float*)d_out);
}

// Round 2
// 155.616 us; speedup vs baseline: 1.0509x; 1.0140x over previous
//
#include <hip/hip_runtime.h>
#include <cmath>

#define Tn  2048
#define Cn  1024
#define Hn  64
#define BTn 16384

typedef _Float16 f16x8 __attribute__((ext_vector_type(8)));
typedef _Float16 f16x4 __attribute__((ext_vector_type(4)));
typedef _Float16 f16x2 __attribute__((ext_vector_type(2)));
typedef float    f32x4 __attribute__((ext_vector_type(4)));

// ---------------------------------------------------------------------------
// prep: transpose Wq|Wk|Wv (each [Cn][64] fp32) into Wt[192][Cn] f16
// ---------------------------------------------------------------------------
__global__ __launch_bounds__(256) void prep_w_kernel(
    const float* __restrict__ Wq, const float* __restrict__ Wk,
    const float* __restrict__ Wv, _Float16* __restrict__ Wt)
{
    __shared__ float ts[64][65];
    const int blk = blockIdx.x;          // 48 = 3 proj * 16 c-tiles
    const int p   = blk >> 4;
    const int c0  = (blk & 15) * 64;
    const float* __restrict__ W = (p == 0) ? Wq : (p == 1) ? Wk : Wv;
    const int tid = threadIdx.x;
    #pragma unroll
    for (int it = 0; it < 16; it++) {
        int idx = tid + it * 256;
        int c = idx >> 6, n = idx & 63;
        ts[c][n] = W[(size_t)(c0 + c) * Hn + n];
    }
    __syncthreads();
    #pragma unroll
    for (int it = 0; it < 16; it++) {
        int idx = tid + it * 256;
        int n = idx >> 6, c = idx & 63;
        Wt[(size_t)(p * 64 + n) * Cn + c0 + c] = (_Float16)ts[c][n];
    }
}

// ---------------------------------------------------------------------------
// proj: K-split 8-wave blocks. Grid is fixed at 512 (= BTn/32) which caps
// occupancy at 2 blocks/CU, so the block itself carries 8 waves (512 thr):
// wave = (kh, wc); kh = K-half (0: K<512, 1: K>=512), wc = col group of 48.
// Each wave computes the FULL 32-row x 48-col tile (acc[2][3], 2:1
// MFMA:B-load ratio) over its K-half; partials combined through LDS (xs
// reused as f32x4 buffer, lane-major = conflict-free), epilogue on waves
// 0-3. 2 blocks/CU x 8 waves = 16 waves/CU = 4 waves/SIMD (was 2 -- the
// round-1 LDS shrink couldn't help because the grid was the cap).
// x staged once (read exactly once from HBM); Wt traffic unchanged 192 MB
// L2. Row stride 1032 f16 = 516 dwords = 4 mod 32: conflict-free frag reads.
// Epilogue: RoPE on q/k (q pre-scaled H^-1/2), v written TRANSPOSED
// vT[b][h][t] so attn can read PV B-frags straight from global.
// ---------------------------------------------------------------------------
#define XSP 1032

__global__ __launch_bounds__(512, 4) void proj_kernel(
    const float* __restrict__ x, const _Float16* __restrict__ Wt,
    _Float16* __restrict__ qh, _Float16* __restrict__ kh_out, _Float16* __restrict__ vT)
{
    __shared__ __align__(16) _Float16 xs[32 * XSP];   // 66 KB -> 2 blocks/CU
    const int row0 = blockIdx.x * 32;
    const int tid  = threadIdx.x;
    const int wave = tid >> 6, lane = tid & 63;
    const int kh   = wave >> 2;          // K-half
    const int wc   = wave & 3;           // col group (48 cols)
    const int quad = lane >> 4, l15 = lane & 15;

    // Stage x (32 rows x 1024 fp32 -> f16) once. Coalesced float4 reads.
    #pragma unroll 8
    for (int it = 0; it < 16; it++) {
        int idx = tid + it * 512;        // 8192 float4 total
        int r = idx >> 8, c4 = idx & 255;
        float4 xv = *(const float4*)&x[(size_t)(row0 + r) * Cn + c4 * 4];
        f16x4 hv = { (_Float16)xv.x, (_Float16)xv.y, (_Float16)xv.z, (_Float16)xv.w };
        *(f16x4*)&xs[r * XSP + c4 * 4] = hv;
    }
    __syncthreads();

    f32x4 acc[2][3] = {};
    const _Float16* __restrict__ wb = Wt + (size_t)(wc * 48 + l15) * Cn
                                         + kh * 512 + quad * 8;
    const _Float16* __restrict__ xp = &xs[kh * 512 + quad * 8];

    #pragma unroll 4
    for (int kc = 0; kc < 512; kc += 32) {
        f16x8 b0 = *(const f16x8*)&wb[kc];
        f16x8 b1 = *(const f16x8*)&wb[16 * Cn + kc];
        f16x8 b2 = *(const f16x8*)&wb[32 * Cn + kc];
        f16x8 a0 = *(const f16x8*)&xp[(     l15) * XSP + kc];
        f16x8 a1 = *(const f16x8*)&xp[(16 + l15) * XSP + kc];
        acc[0][0] = __builtin_amdgcn_mfma_f32_16x16x32_f16(a0, b0, acc[0][0], 0, 0, 0);
        acc[1][0] = __builtin_amdgcn_mfma_f32_16x16x32_f16(a1, b0, acc[1][0], 0, 0, 0);
        acc[0][1] = __builtin_amdgcn_mfma_f32_16x16x32_f16(a0, b1, acc[0][1], 0, 0, 0);
        acc[1][1] = __builtin_amdgcn_mfma_f32_16x16x32_f16(a1, b1, acc[1][1], 0, 0, 0);
        acc[0][2] = __builtin_amdgcn_mfma_f32_16x16x32_f16(a0, b2, acc[0][2], 0, 0, 0);
        acc[1][2] = __builtin_amdgcn_mfma_f32_16x16x32_f16(a1, b2, acc[1][2], 0, 0, 0);
    }

    // Combine the two K-halves: waves 4-7 dump partials into LDS (reuse xs),
    // waves 0-3 add them. Lane-major f32x4 layout = conflict-free.
    __syncthreads();                     // everyone done reading xs
    f32x4* __restrict__ pbuf = (f32x4*)xs;   // 6*256*16B = 24.6 KB
    if (kh) {
        #pragma unroll
        for (int mt = 0; mt < 2; mt++)
            #pragma unroll
            for (int nt = 0; nt < 3; nt++)
                pbuf[(mt * 3 + nt) * 256 + wc * 64 + lane] = acc[mt][nt];
    }
    __syncthreads();
    if (kh) return;
    #pragma unroll
    for (int mt = 0; mt < 2; mt++)
        #pragma unroll
        for (int nt = 0; nt < 3; nt++)
            acc[mt][nt] += pbuf[(mt * 3 + nt) * 256 + wc * 64 + lane];

    // Epilogue (waves 0-3; wc owns cols [wc*48, wc*48+48))
    const int bidx = row0 >> 11;
    #pragma unroll
    for (int nt = 0; nt < 3; nt++) {
        const int n = wc * 48 + nt * 16 + l15;
        const int p = n >> 6;            // uniform per (wc,nt)
        const int h = n & 63;
        if (p < 2) {                     // q or k: RoPE
            _Float16* __restrict__ outb = (p == 0) ? qh : kh_out;
            const float invf = __expf(-0.2878231366242557f * (float)(h >> 1));
            #pragma unroll
            for (int mt = 0; mt < 2; mt++) {
                #pragma unroll
                for (int r = 0; r < 4; r++) {
                    int   row = row0 + mt * 16 + quad * 4 + r;
                    float val = acc[mt][nt][r];
                    float partner = __shfl_xor(val, 1, 64);
                    float ang = (float)(row & (Tn - 1)) * invf;
                    float sv, cv;
                    __sincosf(ang, &sv, &cv);
                    float res = (h & 1) ? fmaf(val, cv,  partner * sv)
                                        : fmaf(val, cv, -partner * sv);
                    if (p == 0) res *= 0.125f;
                    float resn = __shfl_xor(res, 1, 64);
                    if (!(l15 & 1)) {
                        f16x2 pk = { (_Float16)res, (_Float16)resn };
                        *(f16x2*)&outb[(size_t)row * Hn + h] = pk;
                    }
                }
            }
        } else {                         // v: store transposed vT[b][h][t]
            #pragma unroll
            for (int mt = 0; mt < 2; mt++) {
                int t = (row0 & (Tn - 1)) + mt * 16 + quad * 4;
                f16x4 pv = { (_Float16)acc[mt][nt][0], (_Float16)acc[mt][nt][1],
                             (_Float16)acc[mt][nt][2], (_Float16)acc[mt][nt][3] };
                *(f16x4*)&vT[((size_t)bidx * Hn + h) * Tn + t] = pv;
            }
        }
    }
}

// ---------------------------------------------------------------------------
// attn: barrier-free flash loop. QT=16, STL=64, 256 thr = 4 waves; each wave
// processes every 4th s-tile (jt = w, w+4, ...) with its own online-softmax
// state; one barrier + LDS merge at the end. K and vT B-frags read directly
// from global (L2: batch working set 768 KB, XCD-affine via b = blk&7).
// qt permuted so each CU's 4 resident blocks have constant total work.
// ---------------------------------------------------------------------------
#define PSP 72

__global__ __launch_bounds__(256, 4) void attn_kernel(
    const _Float16* __restrict__ qh, const _Float16* __restrict__ kh,
    const _Float16* __restrict__ vT, float* __restrict__ out)
{
    __shared__ _Float16 ps[4][16 * PSP];     // wave-private P transpose
    __shared__ float ocomb[4][16][65];
    __shared__ float mlcomb[4][2][16];       // [wave][m|l][row]

    const int blk = blockIdx.x;
    const int b   = blk & 7;                 // batch == XCD affinity
    const int j   = blk >> 3;                // 0..127
    const int jm  = j & 31, g = j >> 5;      // complement permutation:
    const int qt  = (g == 0) ? (127 - jm)    // per-CU resident set sums const
                  : (g == 1) ? (64 + jm)
                  : (g == 2) ? (63 - jm) : jm;
    const int t0  = qt * 16;
    const int tid = threadIdx.x;
    const int w = tid >> 6, lane = tid & 63;
    const int quad = lane >> 4, l15 = lane & 15;

    const _Float16* __restrict__ qb = qh + (size_t)b * Tn * Hn;
    const _Float16* __restrict__ kb = kh + (size_t)b * Tn * Hn;
    const _Float16* __restrict__ vb = vT + (size_t)b * Hn * Tn;

    // Q A-frags: held in registers for the whole loop
    const f16x8 aq0 = *(const f16x8*)&qb[(size_t)(t0 + l15) * Hn +      quad * 8];
    const f16x8 aq1 = *(const f16x8*)&qb[(size_t)(t0 + l15) * Hn + 32 + quad * 8];

    float m_run[4], l_run[4];
    f32x4 oacc[4] = {};
    #pragma unroll
    for (int r = 0; r < 4; r++) { m_run[r] = -1e30f; l_run[r] = 0.0f; }

    const int nst = (t0 + 16 + 63) >> 6;
    for (int jt = w; jt < nst; jt += 4) {
        const int s0 = jt * 64;

        // K B-frags direct from global (16 rows x 64B per load instr)
        f16x8 kf[4][2];
        #pragma unroll
        for (int nt = 0; nt < 4; nt++) {
            const _Float16* kp = &kb[(size_t)(s0 + nt * 16 + l15) * Hn + quad * 8];
            kf[nt][0] = *(const f16x8*)kp;
            kf[nt][1] = *(const f16x8*)(kp + 32);
        }
        f32x4 sacc[4];
        #pragma unroll
        for (int nt = 0; nt < 4; nt++) {
            f32x4 z = {};
            z = __builtin_amdgcn_mfma_f32_16x16x32_f16(aq0, kf[nt][0], z, 0, 0, 0);
            z = __builtin_amdgcn_mfma_f32_16x16x32_f16(aq1, kf[nt][1], z, 0, 0, 0);
            sacc[nt] = z;
        }

        // vT B-frags: issue before softmax (independent), consumed by PV
        f16x8 vf[2][4];
        #pragma unroll
        for (int sc = 0; sc < 2; sc++)
            #pragma unroll
            for (int ht = 0; ht < 4; ht++)
                vf[sc][ht] = *(const f16x8*)&vb[(size_t)(ht * 16 + l15) * Tn
                                                + s0 + sc * 32 + quad * 8];

        if (jt == nst - 1) {             // causal mask: only diagonal tile
            #pragma unroll
            for (int nt = 0; nt < 4; nt++)
                #pragma unroll
                for (int r = 0; r < 4; r++) {
                    int scol = s0 + nt * 16 + l15;
                    int trow = t0 + quad * 4 + r;
                    if (scol > trow) sacc[nt][r] = -1e30f;
                }
        }

        // online softmax (rows = quad*4+r; reduce over the 16 l15 lanes)
        float pr[4][4];
        #pragma unroll
        for (int r = 0; r < 4; r++) {
            float mx = fmaxf(fmaxf(sacc[0][r], sacc[1][r]),
                             fmaxf(sacc[2][r], sacc[3][r]));
            #pragma unroll
            for (int off = 1; off < 16; off <<= 1)
                mx = fmaxf(mx, __shfl_xor(mx, off, 64));
            float mnew  = fmaxf(m_run[r], mx);
            float alpha = __expf(m_run[r] - mnew);
            m_run[r] = mnew;
            float rs = 0.0f;
            #pragma unroll
            for (int nt = 0; nt < 4; nt++) {
                float pv = __expf(sacc[nt][r] - mnew);
                pr[nt][r] = pv; rs += pv;
            }
            #pragma unroll
            for (int off = 1; off < 16; off <<= 1)
                rs += __shfl_xor(rs, off, 64);
            l_run[r] = fmaf(l_run[r], alpha, rs);
            #pragma unroll
            for (int ht = 0; ht < 4; ht++)
                oacc[ht][r] = oacc[ht][r] * alpha;
        }

        // P -> ps (wave-private; same-wave RAW, no barrier)
        #pragma unroll
        for (int nt = 0; nt < 4; nt++)
            #pragma unroll
            for (int r = 0; r < 4; r++) {
                float pv = pr[nt][r];
                float pn = __shfl_xor(pv, 1, 64);
                if (!(l15 & 1)) {
                    f16x2 pk = { (_Float16)pv, (_Float16)pn };
                    *(f16x2*)&ps[w][(quad * 4 + r) * PSP + nt * 16 + l15] = pk;
                }
            }

        // O += P V  (8 MFMA, B-frags already in registers)
        #pragma unroll
        for (int sc = 0; sc < 2; sc++) {
            f16x8 ap = *(const f16x8*)&ps[w][l15 * PSP + sc * 32 + quad * 8];
            #pragma unroll
            for (int ht = 0; ht < 4; ht++)
                oacc[ht] = __builtin_amdgcn_mfma_f32_16x16x32_f16(ap, vf[sc][ht],
                                                                  oacc[ht], 0, 0, 0);
        }
    }

    // Write partials, barrier, merge the four waves' online-softmax states.
    #pragma unroll
    for (int r = 0; r < 4; r++) {
        #pragma unroll
        for (int ht = 0; ht < 4; ht++)
            ocomb[w][quad * 4 + r][ht * 16 + l15] = oacc[ht][r];
        if (l15 == 0) {
            mlcomb[w][0][quad * 4 + r] = m_run[r];
            mlcomb[w][1][quad * 4 + r] = l_run[r];
        }
    }
    __syncthreads();

    // wave w finalizes rows [w*4, w*4+4); 64 lanes = 64 h (coalesced)
    #pragma unroll
    for (int rp = 0; rp < 4; rp++) {
        int row = w * 4 + rp;
        float m0 = mlcomb[0][0][row], m1 = mlcomb[1][0][row];
        float m2 = mlcomb[2][0][row], m3 = mlcomb[3][0][row];
        float mm = fmaxf(fmaxf(m0, m1), fmaxf(m2, m3));
        float a0 = __expf(m0 - mm), a1 = __expf(m1 - mm);
        float a2 = __expf(m2 - mm), a3 = __expf(m3 - mm);
        float ll = mlcomb[0][1][row] * a0 + mlcomb[1][1][row] * a1
                 + mlcomb[2][1][row] * a2 + mlcomb[3][1][row] * a3;
        float ov = (ocomb[0][row][lane] * a0 + ocomb[1][row][lane] * a1
                  + ocomb[2][row][lane] * a2 + ocomb[3][row][lane] * a3) / ll;
        out[((size_t)b * Tn + t0 + row) * Hn + lane] = ov;
    }
}

extern "C" void kernel_launch(void* const* d_in, const int* in_sizes, int n_in,
                              void* d_out, int out_size, void* d_ws, size_t ws_size,
                              hipStream_t stream) {
    const float* x  = (const float*)d_in[0];
    const float* Wq = (const float*)d_in[1];
    const float* Wk = (const float*)d_in[2];
    const float* Wv = (const float*)d_in[3];

    const size_t qkvN = (size_t)BTn * Hn;
    _Float16* qh = (_Float16*)d_ws;
    _Float16* kh = qh + qkvN;
    _Float16* vT = kh + qkvN;                     // [8][64][2048] transposed
    _Float16* Wt = vT + qkvN;                     // [192][1024] f16

    prep_w_kernel<<<48, 256, 0, stream>>>(Wq, Wk, Wv, Wt);
    proj_kernel<<<BTn / 32, 512, 0, stream>>>(x, Wt, qh, kh, vT);
    attn_kernel<<<1024, 256, 0, stream>>>(qh, kh, vT, (float*)d_out);
}